// Round 1
// baseline (20.147 us; speedup 1.0000x reference)
//
#include <hip/hip_runtime.h>

// DeepFM fused forward for MI355X (gfx950).
// Batch 2048, 8 fields, embed 16, MLP 128->256->128->64->1.
// One wave (64 lanes) per block; each wave computes EPB=4 batch rows,
// sharing every weight load across the 4 rows (4x L2 traffic reduction).

#define NF   8
#define ED   16
#define IN0  128   // NF*ED
#define N1   256
#define N2   128
#define N3   64
#define EPB  4     // batch elements per block (per wave)

__device__ const int g_off[NF] = {0, 50000, 55000, 57000, 58000, 59000, 59500, 59800};

__global__ __launch_bounds__(64) void deepfm_fused(
    const int*   __restrict__ x,     // [B, NF] int32
    const float* __restrict__ emb,   // [60000, 16]
    const float* __restrict__ wlin,  // [60000]
    const float* __restrict__ blin,  // [1]
    const float* __restrict__ w1,    // [128, 256]
    const float* __restrict__ b1,    // [256]
    const float* __restrict__ w2,    // [256, 128]
    const float* __restrict__ b2,    // [128]
    const float* __restrict__ w3,    // [128, 64]
    const float* __restrict__ b3,    // [64]
    const float* __restrict__ wlast, // [64]
    float*       __restrict__ out)   // [B]
{
    __shared__ float h0[EPB][IN0];
    __shared__ float h1[EPB][N1];
    __shared__ float h2[EPB][N2];
    __shared__ float base[EPB];

    const int lane = threadIdx.x;
    const int b0   = blockIdx.x * EPB;

    // ---- embedding gather: lane -> (e, f, half); 8 floats per lane ----
    {
        const int e    = lane >> 4;
        const int f    = (lane >> 1) & 7;
        const int half = lane & 1;
        const int idx  = x[(b0 + e) * NF + f] + g_off[f];
        const float4* src = (const float4*)(emb + idx * ED + half * 8);
        float4 a = src[0];
        float4 c = src[1];
        float4* dst = (float4*)(&h0[e][f * ED + half * 8]);
        dst[0] = a;
        dst[1] = c;
    }

    // ---- sparse linear term: lanes 0..31 -> (e, f) ----
    float lin = 0.0f;
    if (lane < 32) {
        const int e   = lane >> 3;
        const int f   = lane & 7;
        const int idx = x[(b0 + e) * NF + f] + g_off[f];
        lin = wlin[idx];
    }
    lin += __shfl_xor(lin, 1);
    lin += __shfl_xor(lin, 2);
    lin += __shfl_xor(lin, 4);
    if (lane < 32 && (lane & 7) == 0) base[lane >> 3] = lin;

    __syncthreads();

    // ---- FM second-order term: lane -> (e, d) ----
    {
        const int e = lane >> 4;
        const int d = lane & 15;
        float s = 0.0f, ss = 0.0f;
        #pragma unroll
        for (int f = 0; f < NF; ++f) {
            const float v = h0[e][f * ED + d];
            s += v;
            ss = fmaf(v, v, ss);
        }
        float p = 0.5f * (s * s - ss);
        p += __shfl_xor(p, 1);
        p += __shfl_xor(p, 2);
        p += __shfl_xor(p, 4);
        p += __shfl_xor(p, 8);
        if (d == 0) base[e] += p + blin[0];
    }

    // ---- layer 1: h0[128] @ w1[128,256] -> h1[256]; lane owns cols lane*4..+3 ----
    const float4 bv1 = *(const float4*)(b1 + lane * 4);
    float4 acc1[EPB];
    #pragma unroll
    for (int e = 0; e < EPB; ++e) acc1[e] = bv1;

    for (int k0 = 0; k0 < IN0; k0 += 4) {
        float4 hv[EPB];
        #pragma unroll
        for (int e = 0; e < EPB; ++e) hv[e] = *(const float4*)(&h0[e][k0]);
        #pragma unroll
        for (int i = 0; i < 4; ++i) {
            const float4 w = *(const float4*)(w1 + (k0 + i) * N1 + lane * 4);
            #pragma unroll
            for (int e = 0; e < EPB; ++e) {
                const float hk = (i == 0) ? hv[e].x : (i == 1) ? hv[e].y
                               : (i == 2) ? hv[e].z : hv[e].w;
                acc1[e].x = fmaf(hk, w.x, acc1[e].x);
                acc1[e].y = fmaf(hk, w.y, acc1[e].y);
                acc1[e].z = fmaf(hk, w.z, acc1[e].z);
                acc1[e].w = fmaf(hk, w.w, acc1[e].w);
            }
        }
    }
    #pragma unroll
    for (int e = 0; e < EPB; ++e) {
        float4 r;
        r.x = fmaxf(acc1[e].x, 0.0f);
        r.y = fmaxf(acc1[e].y, 0.0f);
        r.z = fmaxf(acc1[e].z, 0.0f);
        r.w = fmaxf(acc1[e].w, 0.0f);
        *(float4*)(&h1[e][lane * 4]) = r;
    }
    __syncthreads();

    // ---- layer 2: h1[256] @ w2[256,128] -> h2[128]; lane owns cols lane*2..+1 ----
    const float2 bv2 = *(const float2*)(b2 + lane * 2);
    float2 acc2[EPB];
    #pragma unroll
    for (int e = 0; e < EPB; ++e) acc2[e] = bv2;

    for (int k0 = 0; k0 < N1; k0 += 4) {
        float4 hv[EPB];
        #pragma unroll
        for (int e = 0; e < EPB; ++e) hv[e] = *(const float4*)(&h1[e][k0]);
        #pragma unroll
        for (int i = 0; i < 4; ++i) {
            const float2 w = *(const float2*)(w2 + (k0 + i) * N2 + lane * 2);
            #pragma unroll
            for (int e = 0; e < EPB; ++e) {
                const float hk = (i == 0) ? hv[e].x : (i == 1) ? hv[e].y
                               : (i == 2) ? hv[e].z : hv[e].w;
                acc2[e].x = fmaf(hk, w.x, acc2[e].x);
                acc2[e].y = fmaf(hk, w.y, acc2[e].y);
            }
        }
    }
    #pragma unroll
    for (int e = 0; e < EPB; ++e) {
        float2 r;
        r.x = fmaxf(acc2[e].x, 0.0f);
        r.y = fmaxf(acc2[e].y, 0.0f);
        *(float2*)(&h2[e][lane * 2]) = r;
    }
    __syncthreads();

    // ---- layer 3: h2[128] @ w3[128,64] -> h3[64]; lane owns col = lane ----
    const float bv3 = b3[lane];
    float acc3[EPB];
    #pragma unroll
    for (int e = 0; e < EPB; ++e) acc3[e] = bv3;

    for (int k0 = 0; k0 < N2; k0 += 4) {
        float4 hv[EPB];
        #pragma unroll
        for (int e = 0; e < EPB; ++e) hv[e] = *(const float4*)(&h2[e][k0]);
        #pragma unroll
        for (int i = 0; i < 4; ++i) {
            const float w = w3[(k0 + i) * N3 + lane];
            #pragma unroll
            for (int e = 0; e < EPB; ++e) {
                const float hk = (i == 0) ? hv[e].x : (i == 1) ? hv[e].y
                               : (i == 2) ? hv[e].z : hv[e].w;
                acc3[e] = fmaf(hk, w, acc3[e]);
            }
        }
    }

    // ---- final: y_dnn = relu(h3) . wlast; full-wave butterfly reduce ----
    const float wl = wlast[lane];
    float t0 = fmaxf(acc3[0], 0.0f) * wl;
    float t1 = fmaxf(acc3[1], 0.0f) * wl;
    float t2 = fmaxf(acc3[2], 0.0f) * wl;
    float t3 = fmaxf(acc3[3], 0.0f) * wl;
    #pragma unroll
    for (int off = 1; off < 64; off <<= 1) {
        t0 += __shfl_xor(t0, off);
        t1 += __shfl_xor(t1, off);
        t2 += __shfl_xor(t2, off);
        t3 += __shfl_xor(t3, off);
    }
    if (lane == 0) {
        out[b0 + 0] = base[0] + t0;
        out[b0 + 1] = base[1] + t1;
        out[b0 + 2] = base[2] + t2;
        out[b0 + 3] = base[3] + t3;
    }
}

extern "C" void kernel_launch(void* const* d_in, const int* in_sizes, int n_in,
                              void* d_out, int out_size, void* d_ws, size_t ws_size,
                              hipStream_t stream) {
    const int*   x     = (const int*)d_in[0];
    const float* emb   = (const float*)d_in[1];
    const float* wlin  = (const float*)d_in[2];
    const float* blin  = (const float*)d_in[3];
    const float* w1    = (const float*)d_in[4];
    const float* b1    = (const float*)d_in[5];
    const float* w2    = (const float*)d_in[6];
    const float* b2    = (const float*)d_in[7];
    const float* w3    = (const float*)d_in[8];
    const float* b3    = (const float*)d_in[9];
    const float* wlast = (const float*)d_in[10];
    float* out = (float*)d_out;

    const int batch = in_sizes[0] / NF;   // 2048
    dim3 grid(batch / EPB);               // 512 blocks, 1 wave each
    deepfm_fused<<<grid, 64, 0, stream>>>(x, emb, wlin, blin,
                                          w1, b1, w2, b2, w3, b3, wlast, out);
}

// Round 2
// 15.871 us; speedup vs baseline: 1.2694x; 1.2694x over previous
//
#include <hip/hip_runtime.h>

// DeepFM fused forward, round 2: 256-thread blocks (4 waves), column-split
// MLP so weights are read once per block; EPB=4 rows/block, grid=512.
// Occupancy 2 -> 8 waves/CU, same per-block L2 weight traffic.

#define NF   8
#define ED   16
#define IN0  128   // NF*ED
#define N1   256
#define N2   128
#define N3   64
#define EPB  4     // batch rows per block
#define T    256   // threads per block (4 waves)

__device__ const int g_off[NF] = {0, 50000, 55000, 57000, 58000, 59000, 59500, 59800};

__global__ __launch_bounds__(T) void deepfm_fused(
    const int*   __restrict__ x,     // [B, NF] int32
    const float* __restrict__ emb,   // [60000, 16]
    const float* __restrict__ wlin,  // [60000]
    const float* __restrict__ blin,  // [1]
    const float* __restrict__ w1,    // [128, 256]
    const float* __restrict__ b1,    // [256]
    const float* __restrict__ w2,    // [256, 128]
    const float* __restrict__ b2,    // [128]
    const float* __restrict__ w3,    // [128, 64]
    const float* __restrict__ b3,    // [64]
    const float* __restrict__ wlast, // [64]
    float*       __restrict__ out)   // [B]
{
    __shared__ float h0[EPB][IN0];
    __shared__ float h1[EPB][N1];
    __shared__ float h2[EPB][N2];
    __shared__ float ps2[EPB][N2];      // layer-2 upper-half partials
    __shared__ float ps3[3][EPB][N3];   // layer-3 seg 1..3 partials
    __shared__ float base[EPB];

    const int tid = threadIdx.x;
    const int b0  = blockIdx.x * EPB;

    // ---- embedding gather: each thread loads 2 floats ----
    {
        const int r = tid >> 6;        // row 0..3
        const int f = (tid >> 3) & 7;  // field 0..7
        const int p = tid & 7;         // pair 0..7
        const int idx = x[(b0 + r) * NF + f] + g_off[f];
        const float2 v = *(const float2*)(emb + idx * ED + p * 2);
        *(float2*)(&h0[r][f * ED + p * 2]) = v;
    }

    // ---- sparse linear term: wave 0, lanes 0..31 ----
    if (tid < 32) {
        const int r = tid >> 3, f = tid & 7;
        float lin = wlin[x[(b0 + r) * NF + f] + g_off[f]];
        lin += __shfl_xor(lin, 1);
        lin += __shfl_xor(lin, 2);
        lin += __shfl_xor(lin, 4);
        if ((tid & 7) == 0) base[r] = lin + blin[0];
    }
    __syncthreads();

    // ---- FM second-order: wave 0, 64 lanes (same wave as linear => ordered)
    if (tid < 64) {
        const int r = tid >> 4, d = tid & 15;
        float s = 0.0f, ss = 0.0f;
        #pragma unroll
        for (int f = 0; f < NF; ++f) {
            const float v = h0[r][f * ED + d];
            s += v;
            ss = fmaf(v, v, ss);
        }
        float p = 0.5f * (s * s - ss);
        p += __shfl_xor(p, 1);
        p += __shfl_xor(p, 2);
        p += __shfl_xor(p, 4);
        p += __shfl_xor(p, 8);
        if (d == 0) base[r] += p;
    }

    // ---- layer 1: h0[128] @ w1[128,256]; thread owns col = tid ----
    {
        float acc[EPB];
        const float bb = b1[tid];
        #pragma unroll
        for (int e = 0; e < EPB; ++e) acc[e] = bb;

        #pragma unroll 4
        for (int k0 = 0; k0 < IN0; k0 += 4) {
            float4 hv[EPB];
            #pragma unroll
            for (int e = 0; e < EPB; ++e) hv[e] = *(const float4*)(&h0[e][k0]);
            #pragma unroll
            for (int i = 0; i < 4; ++i) {
                const float w = w1[(k0 + i) * N1 + tid];
                #pragma unroll
                for (int e = 0; e < EPB; ++e) {
                    const float hk = (i == 0) ? hv[e].x : (i == 1) ? hv[e].y
                                   : (i == 2) ? hv[e].z : hv[e].w;
                    acc[e] = fmaf(hk, w, acc[e]);
                }
            }
        }
        #pragma unroll
        for (int e = 0; e < EPB; ++e) h1[e][tid] = fmaxf(acc[e], 0.0f);
    }
    __syncthreads();

    // ---- layer 2: h1[256] @ w2[256,128]; col = tid&127, K-half = tid>>7 ----
    {
        const int c     = tid & (N2 - 1);
        const int half  = tid >> 7;
        const int kbase = half * 128;
        float acc[EPB];
        #pragma unroll
        for (int e = 0; e < EPB; ++e) acc[e] = 0.0f;

        #pragma unroll 4
        for (int k0 = 0; k0 < 128; k0 += 4) {
            float4 hv[EPB];
            #pragma unroll
            for (int e = 0; e < EPB; ++e) hv[e] = *(const float4*)(&h1[e][kbase + k0]);
            #pragma unroll
            for (int i = 0; i < 4; ++i) {
                const float w = w2[(kbase + k0 + i) * N2 + c];
                #pragma unroll
                for (int e = 0; e < EPB; ++e) {
                    const float hk = (i == 0) ? hv[e].x : (i == 1) ? hv[e].y
                                   : (i == 2) ? hv[e].z : hv[e].w;
                    acc[e] = fmaf(hk, w, acc[e]);
                }
            }
        }
        if (half == 1) {
            #pragma unroll
            for (int e = 0; e < EPB; ++e) ps2[e][c] = acc[e];
        }
        __syncthreads();
        if (half == 0) {
            const float bb = b2[c];
            #pragma unroll
            for (int e = 0; e < EPB; ++e)
                h2[e][c] = fmaxf(acc[e] + ps2[e][c] + bb, 0.0f);
        }
    }
    __syncthreads();

    // ---- layer 3: h2[128] @ w3[128,64]; col = tid&63, K-seg = tid>>6 ----
    {
        const int c     = tid & (N3 - 1);
        const int seg   = tid >> 6;
        const int kbase = seg * 32;
        float acc[EPB];
        #pragma unroll
        for (int e = 0; e < EPB; ++e) acc[e] = 0.0f;

        #pragma unroll
        for (int k0 = 0; k0 < 32; k0 += 4) {
            float4 hv[EPB];
            #pragma unroll
            for (int e = 0; e < EPB; ++e) hv[e] = *(const float4*)(&h2[e][kbase + k0]);
            #pragma unroll
            for (int i = 0; i < 4; ++i) {
                const float w = w3[(kbase + k0 + i) * N3 + c];
                #pragma unroll
                for (int e = 0; e < EPB; ++e) {
                    const float hk = (i == 0) ? hv[e].x : (i == 1) ? hv[e].y
                                   : (i == 2) ? hv[e].z : hv[e].w;
                    acc[e] = fmaf(hk, w, acc[e]);
                }
            }
        }
        if (seg != 0) {
            #pragma unroll
            for (int e = 0; e < EPB; ++e) ps3[seg - 1][e][c] = acc[e];
        }
        __syncthreads();

        // ---- finale: wave 0 combines segs, relu, dot with wlast, reduce ----
        if (tid < 64) {
            const float bb = b3[c];
            const float wl = wlast[c];
            float t[EPB];
            #pragma unroll
            for (int e = 0; e < EPB; ++e) {
                const float v = acc[e] + ps3[0][e][c] + ps3[1][e][c] + ps3[2][e][c] + bb;
                t[e] = fmaxf(v, 0.0f) * wl;
            }
            #pragma unroll
            for (int off = 1; off < 64; off <<= 1) {
                #pragma unroll
                for (int e = 0; e < EPB; ++e) t[e] += __shfl_xor(t[e], off);
            }
            if (tid == 0) {
                #pragma unroll
                for (int e = 0; e < EPB; ++e) out[b0 + e] = base[e] + t[e];
            }
        }
    }
}

extern "C" void kernel_launch(void* const* d_in, const int* in_sizes, int n_in,
                              void* d_out, int out_size, void* d_ws, size_t ws_size,
                              hipStream_t stream) {
    const int*   x     = (const int*)d_in[0];
    const float* emb   = (const float*)d_in[1];
    const float* wlin  = (const float*)d_in[2];
    const float* blin  = (const float*)d_in[3];
    const float* w1    = (const float*)d_in[4];
    const float* b1    = (const float*)d_in[5];
    const float* w2    = (const float*)d_in[6];
    const float* b2    = (const float*)d_in[7];
    const float* w3    = (const float*)d_in[8];
    const float* b3    = (const float*)d_in[9];
    const float* wlast = (const float*)d_in[10];
    float* out = (float*)d_out;

    const int batch = in_sizes[0] / NF;   // 2048
    dim3 grid(batch / EPB);               // 512 blocks x 256 threads
    deepfm_fused<<<grid, T, 0, stream>>>(x, emb, wlin, blin,
                                         w1, b1, w2, b2, w3, b3, wlast, out);
}

// Round 3
// 13.938 us; speedup vs baseline: 1.4455x; 1.1387x over previous
//
#include <hip/hip_runtime.h>

// DeepFM fused forward, round 3.
// grid=256 blocks (1/CU) x 512 threads (8 waves); EPB=8 rows/block.
// Weights read once per block (split-K + LDS combine) -> 75 MB total L2 traffic.
// float2 weight loads + 8-row ILP per weight load to hide L2 latency.

#define NF   8
#define ED   16
#define IN0  128   // NF*ED
#define N1   256
#define N2   128
#define N3   64
#define EPB  8     // batch rows per block
#define T    512   // threads per block (8 waves)

__device__ const int g_off[NF] = {0, 50000, 55000, 57000, 58000, 59000, 59500, 59800};

__global__ __launch_bounds__(T) void deepfm_fused(
    const int*   __restrict__ x,     // [B, NF]
    const float* __restrict__ emb,   // [60000, 16]
    const float* __restrict__ wlin,  // [60000]
    const float* __restrict__ blin,  // [1]
    const float* __restrict__ w1,    // [128, 256]
    const float* __restrict__ b1,    // [256]
    const float* __restrict__ w2,    // [256, 128]
    const float* __restrict__ b2,    // [128]
    const float* __restrict__ w3,    // [128, 64]
    const float* __restrict__ b3,    // [64]
    const float* __restrict__ wlast, // [64]
    float*       __restrict__ out)   // [B]
{
    __shared__ float h0[EPB][IN0];   // 4 KB
    __shared__ float h1[EPB][N1];    // 8 KB
    __shared__ float h2[EPB][N2];    // 4 KB
    __shared__ float ps[7 * EPB * N2]; // 28 KB, unioned split-K partials
    __shared__ float base[EPB];

    const int tid = threadIdx.x;
    const int b0  = blockIdx.x * EPB;

    // ---- embedding gather: 8 rows x 8 fields x 16 -> 512 threads x float2 ----
    {
        const int r = tid >> 6;        // row 0..7
        const int f = (tid >> 3) & 7;  // field 0..7
        const int p = tid & 7;         // pair 0..7
        const int idx = x[(b0 + r) * NF + f] + g_off[f];
        *(float2*)(&h0[r][f * ED + p * 2]) = *(const float2*)(emb + idx * ED + p * 2);
    }

    // ---- sparse linear: wave 0, 64 lanes = 8 rows x 8 fields ----
    if (tid < 64) {
        const int r = tid >> 3, f = tid & 7;
        float lin = wlin[x[(b0 + r) * NF + f] + g_off[f]];
        lin += __shfl_xor(lin, 1);
        lin += __shfl_xor(lin, 2);
        lin += __shfl_xor(lin, 4);
        if (f == 0) base[r] = lin + blin[0];
    }
    __syncthreads();   // B1: h0 + base ready

    // ---- FM second-order: waves 0-1, 128 threads = 8 rows x 16 dims ----
    if (tid < 128) {
        const int r = tid >> 4, d = tid & 15;
        float s = 0.0f, ss = 0.0f;
        #pragma unroll
        for (int f = 0; f < NF; ++f) {
            const float v = h0[r][f * ED + d];
            s += v;
            ss = fmaf(v, v, ss);
        }
        float p = 0.5f * (s * s - ss);
        p += __shfl_xor(p, 1);
        p += __shfl_xor(p, 2);
        p += __shfl_xor(p, 4);
        p += __shfl_xor(p, 8);
        if (d == 0) base[r] += p;
    }

    // ---- layer 1: h0[8,128] @ w1[128,256] -> h1[8,256] ----
    // thread: cols c2,c2+1 (c2=(tid&127)*2), K-seg tid>>7 (4 segs x K=32)
    {
        const int c2    = (tid & 127) * 2;
        const int seg   = tid >> 7;
        const int kbase = seg * 32;
        float2 acc[EPB];
        const float2 bb = (seg == 0) ? *(const float2*)(b1 + c2) : make_float2(0.f, 0.f);
        #pragma unroll
        for (int e = 0; e < EPB; ++e) acc[e] = bb;

        #pragma unroll 2
        for (int k0 = 0; k0 < 32; k0 += 4) {
            float4 hv[EPB];
            #pragma unroll
            for (int e = 0; e < EPB; ++e) hv[e] = *(const float4*)(&h0[e][kbase + k0]);
            #pragma unroll
            for (int i = 0; i < 4; ++i) {
                const float2 w = *(const float2*)(w1 + (kbase + k0 + i) * N1 + c2);
                #pragma unroll
                for (int e = 0; e < EPB; ++e) {
                    const float hk = (i == 0) ? hv[e].x : (i == 1) ? hv[e].y
                                   : (i == 2) ? hv[e].z : hv[e].w;
                    acc[e].x = fmaf(hk, w.x, acc[e].x);
                    acc[e].y = fmaf(hk, w.y, acc[e].y);
                }
            }
        }
        if (seg != 0) {
            #pragma unroll
            for (int e = 0; e < EPB; ++e)
                *(float2*)(&ps[(seg - 1) * (EPB * N1) + e * N1 + c2]) = acc[e];
        }
        __syncthreads();   // B2: ps1 ready
        if (seg == 0) {
            #pragma unroll
            for (int e = 0; e < EPB; ++e) {
                float2 v = acc[e];
                #pragma unroll
                for (int s = 0; s < 3; ++s) {
                    const float2 q = *(const float2*)(&ps[s * (EPB * N1) + e * N1 + c2]);
                    v.x += q.x; v.y += q.y;
                }
                h1[e][c2]     = fmaxf(v.x, 0.0f);
                h1[e][c2 + 1] = fmaxf(v.y, 0.0f);
            }
        }
    }
    __syncthreads();   // B3: h1 ready, ps reusable

    // ---- layer 2: h1[8,256] @ w2[256,128] -> h2[8,128] ----
    // thread: cols c2,c2+1 (c2=(tid&63)*2), K-seg tid>>6 (8 segs x K=32)
    {
        const int c2    = (tid & 63) * 2;
        const int seg   = tid >> 6;
        const int kbase = seg * 32;
        float2 acc[EPB];
        #pragma unroll
        for (int e = 0; e < EPB; ++e) acc[e] = make_float2(0.f, 0.f);

        #pragma unroll 2
        for (int k0 = 0; k0 < 32; k0 += 4) {
            float4 hv[EPB];
            #pragma unroll
            for (int e = 0; e < EPB; ++e) hv[e] = *(const float4*)(&h1[e][kbase + k0]);
            #pragma unroll
            for (int i = 0; i < 4; ++i) {
                const float2 w = *(const float2*)(w2 + (kbase + k0 + i) * N2 + c2);
                #pragma unroll
                for (int e = 0; e < EPB; ++e) {
                    const float hk = (i == 0) ? hv[e].x : (i == 1) ? hv[e].y
                                   : (i == 2) ? hv[e].z : hv[e].w;
                    acc[e].x = fmaf(hk, w.x, acc[e].x);
                    acc[e].y = fmaf(hk, w.y, acc[e].y);
                }
            }
        }
        if (seg != 0) {
            #pragma unroll
            for (int e = 0; e < EPB; ++e)
                *(float2*)(&ps[(seg - 1) * (EPB * N2) + e * N2 + c2]) = acc[e];
        }
        __syncthreads();   // B4: ps2 ready
        if (seg == 0) {
            const float2 bb = *(const float2*)(b2 + c2);
            #pragma unroll
            for (int e = 0; e < EPB; ++e) {
                float2 v = acc[e];
                #pragma unroll
                for (int s = 0; s < 7; ++s) {
                    const float2 q = *(const float2*)(&ps[s * (EPB * N2) + e * N2 + c2]);
                    v.x += q.x; v.y += q.y;
                }
                h2[e][c2]     = fmaxf(v.x + bb.x, 0.0f);
                h2[e][c2 + 1] = fmaxf(v.y + bb.y, 0.0f);
            }
        }
    }
    __syncthreads();   // B5: h2 ready, ps reusable

    // ---- layer 3: h2[8,128] @ w3[128,64]; col=tid&63, K-seg tid>>6 (8 x K=16) ----
    {
        const int c     = tid & 63;
        const int seg   = tid >> 6;
        const int kbase = seg * 16;
        float acc[EPB];
        #pragma unroll
        for (int e = 0; e < EPB; ++e) acc[e] = 0.0f;

        #pragma unroll
        for (int k0 = 0; k0 < 16; k0 += 4) {
            float4 hv[EPB];
            #pragma unroll
            for (int e = 0; e < EPB; ++e) hv[e] = *(const float4*)(&h2[e][kbase + k0]);
            #pragma unroll
            for (int i = 0; i < 4; ++i) {
                const float w = w3[(kbase + k0 + i) * N3 + c];
                #pragma unroll
                for (int e = 0; e < EPB; ++e) {
                    const float hk = (i == 0) ? hv[e].x : (i == 1) ? hv[e].y
                                   : (i == 2) ? hv[e].z : hv[e].w;
                    acc[e] = fmaf(hk, w, acc[e]);
                }
            }
        }
        if (seg != 0) {
            #pragma unroll
            for (int e = 0; e < EPB; ++e)
                ps[(seg - 1) * (EPB * N3) + e * N3 + c] = acc[e];
        }
        __syncthreads();   // B6: ps3 ready

        // ---- finale on wave 0 ----
        if (tid < 64) {
            const float bb = b3[c];
            const float wl = wlast[c];
            float t[EPB];
            #pragma unroll
            for (int e = 0; e < EPB; ++e) {
                float v = acc[e] + bb;
                #pragma unroll
                for (int s = 0; s < 7; ++s) v += ps[s * (EPB * N3) + e * N3 + c];
                t[e] = fmaxf(v, 0.0f) * wl;
            }
            #pragma unroll
            for (int off = 1; off < 64; off <<= 1) {
                #pragma unroll
                for (int e = 0; e < EPB; ++e) t[e] += __shfl_xor(t[e], off);
            }
            if (tid == 0) {
                #pragma unroll
                for (int e = 0; e < EPB; ++e) out[b0 + e] = base[e] + t[e];
            }
        }
    }
}

extern "C" void kernel_launch(void* const* d_in, const int* in_sizes, int n_in,
                              void* d_out, int out_size, void* d_ws, size_t ws_size,
                              hipStream_t stream) {
    const int*   x     = (const int*)d_in[0];
    const float* emb   = (const float*)d_in[1];
    const float* wlin  = (const float*)d_in[2];
    const float* blin  = (const float*)d_in[3];
    const float* w1    = (const float*)d_in[4];
    const float* b1    = (const float*)d_in[5];
    const float* w2    = (const float*)d_in[6];
    const float* b2    = (const float*)d_in[7];
    const float* w3    = (const float*)d_in[8];
    const float* b3    = (const float*)d_in[9];
    const float* wlast = (const float*)d_in[10];
    float* out = (float*)d_out;

    const int batch = in_sizes[0] / NF;   // 2048
    dim3 grid(batch / EPB);               // 256 blocks x 512 threads
    deepfm_fused<<<grid, T, 0, stream>>>(x, emb, wlin, blin,
                                         w1, b1, w2, b2, w3, b3, wlast, out);
}